// Round 1
// baseline (854.063 us; speedup 1.0000x reference)
//
#include <hip/hip_runtime.h>
#include <math.h>

#define H 512
#define B 32
#define S 1024
#define V 50000

// ---- workspace layout (float offsets) ----
#define ZT_OFF   0         // zT [1536][32]
#define GT_OFF   49152     // gatesT [2048][32]
#define CT_OFF   114688    // cT [512][32]
#define Q_OFF    131072    // q [32][512]
#define YT_OFF   147456    // yT [1024][32]
#define SC_OFF   180224    // scores [32][1024]
#define PAR_OFF  212992    // partial ctx [32][32][512]
#define LSEP_OFF 737280    // lse partials [32][16][2]

// ---- d_out layout (float offsets) ----
#define DO_OUT   0         // [B][V] log-softmax
#define DO_CTX   1600000   // [B][H]
#define DO_H     1616384   // [B][H]
#define DO_C     1632768   // [B][H]
#define DO_ATTN  1649152   // [B][S]

// async 16B global->LDS (gfx950). LDS dest = base + lane*16 (linear, wave-level).
__device__ __forceinline__ void gld16(const float* g, float* l) {
    __builtin_amdgcn_global_load_lds(
        (const __attribute__((address_space(1))) void*)g,
        (__attribute__((address_space(3))) void*)l,
        16, 0, 0);
}

// ============ k_prep: zT fill + q = we @ W_a (4-way k-split) ============
// grid 256: b = blk>>3, hq = blk&7 (64 h per block); 256 thr = 4 kg x 64 hl
__global__ void k_prep(const int* __restrict__ wi, const float* __restrict__ lc,
                       const float* __restrict__ h0, const float* __restrict__ emb,
                       const float* __restrict__ Wa,
                       float* __restrict__ zT, float* __restrict__ q) {
    __shared__ float ech[512];
    __shared__ float red[4][64];
    int t = threadIdx.x;
    int b = blockIdx.x >> 3, hq = blockIdx.x & 7;
    int hl = t & 63, kg = t >> 6;
    int h = hq * 64 + hl;
    const float* er = emb + (long long)wi[b] * H;
    ech[t] = er[t];
    ech[256 + t] = er[256 + t];
    __syncthreads();
    if (kg == 0)      zT[h * 32 + b]           = ech[h];          // x part 1
    else if (kg == 1) zT[(H + h) * 32 + b]     = lc[b * H + h];   // x part 2
    else if (kg == 2) zT[(2 * H + h) * 32 + b] = h0[b * H + h];   // hidden
    float acc = 0.f;
    #pragma unroll 8
    for (int j = 0; j < 128; ++j) {
        int k = kg * 128 + j;
        acc += ech[k] * Wa[k * H + h];
    }
    red[kg][hl] = acc;
    __syncthreads();
    if (kg == 0) q[b * H + h] = red[0][hl] + red[1][hl] + red[2][hl] + red[3][hl];
}

// ============ k_gates: one block per gate row r; gatesT[r][b] ============
__global__ void k_gates(const float* __restrict__ zT, const float* __restrict__ Wih,
                        const float* __restrict__ Whh, const float* __restrict__ bih,
                        const float* __restrict__ bhh, float* __restrict__ gT) {
    __shared__ float red[8][32];
    int r = blockIdx.x;                 // 0..2047
    int t = threadIdx.x;
    int kg = t >> 5, b = t & 31;
    int k0 = kg * 192;
    const float* wih_r = Wih + (long long)r * 1024;
    const float* whh_r = Whh + (long long)r * 512;
    float acc = 0.f;
    int n_ih = (k0 < 1024) ? ((1024 - k0 < 192) ? (1024 - k0) : 192) : 0;
    #pragma unroll 4
    for (int j = 0; j < n_ih; ++j) {
        int k = k0 + j;
        acc += wih_r[k] * zT[k * 32 + b];
    }
    #pragma unroll 4
    for (int j = n_ih; j < 192; ++j) {
        int k = k0 + j;
        acc += whh_r[k - 1024] * zT[k * 32 + b];
    }
    red[kg][b] = acc;
    __syncthreads();
    if (t < 32) {
        float s = bih[r] + bhh[r];
        #pragma unroll
        for (int kk = 0; kk < 8; ++kk) s += red[kk][t];
        gT[r * 32 + t] = s;
    }
}

// ============ k_point: LSTM pointwise. layer 0 feeds zT, layer 1 finalizes ====
__global__ void k_point(const float* __restrict__ gT, const float* __restrict__ cprev,
                        int layer, float* __restrict__ zT, float* __restrict__ cT,
                        float* __restrict__ yT, float* __restrict__ hOut,
                        float* __restrict__ cOut) {
    int t = blockIdx.x * 256 + threadIdx.x;      // 0..16383
    int b = t & 31, hi = t >> 5;
    float gi = gT[hi * 32 + b];
    float gf = gT[(512 + hi) * 32 + b];
    float gg = gT[(1024 + hi) * 32 + b];
    float go = gT[(1536 + hi) * 32 + b];
    float si = 1.f / (1.f + expf(-gi));
    float sf = 1.f / (1.f + expf(-gf));
    float so = 1.f / (1.f + expf(-go));
    float c = (layer == 0) ? cprev[b * H + hi] : cprev[hi * 32 + b];
    float cn = sf * c + si * tanhf(gg);
    float hn = so * tanhf(cn);
    if (layer == 0) {
        zT[hi * 32 + b] = hn;                 // next x part 1
        zT[(2 * H + hi) * 32 + b] = hn;       // next hidden
        cT[hi * 32 + b] = cn;
    } else {
        yT[hi * 32 + b] = hn;                 // y = [h2, ctx], first half
        hOut[b * H + hi] = hn;
        cOut[b * H + hi] = cn;
    }
}

// ============ k_scores: one wave per (b,s) dot(q_b, enc_sb) ============
__global__ void k_scores(const float* __restrict__ q, const float* __restrict__ enc,
                         float* __restrict__ sc) {
    int w = (blockIdx.x * 256 + threadIdx.x) >> 6;   // 0..32767
    int lane = threadIdx.x & 63;
    int b = w >> 10, s = w & 1023;
    const float4* e4 = (const float4*)(enc + ((long long)(s * 32 + b)) * H);
    const float4* q4 = (const float4*)(q + b * H);
    float4 a0 = e4[lane * 2], a1 = e4[lane * 2 + 1];
    float4 b0 = q4[lane * 2], b1 = q4[lane * 2 + 1];
    float v = a0.x * b0.x + a0.y * b0.y + a0.z * b0.z + a0.w * b0.w
            + a1.x * b1.x + a1.y * b1.y + a1.z * b1.z + a1.w * b1.w;
    #pragma unroll
    for (int off = 32; off > 0; off >>= 1) v += __shfl_xor(v, off);
    if (lane == 0) sc[b * S + s] = v;
}

// ============ k_softmax: block per b over S=1024 ============
__global__ void k_softmax(const float* __restrict__ sc, float* __restrict__ attn) {
    __shared__ float red[8];
    int b = blockIdx.x, t = threadIdx.x;
    float v[4];
    float m = -1e30f;
    #pragma unroll
    for (int i = 0; i < 4; ++i) {
        v[i] = sc[b * S + i * 256 + t];
        m = fmaxf(m, v[i]);
    }
    #pragma unroll
    for (int off = 32; off > 0; off >>= 1) m = fmaxf(m, __shfl_xor(m, off));
    if ((t & 63) == 0) red[t >> 6] = m;
    __syncthreads();
    m = fmaxf(fmaxf(red[0], red[1]), fmaxf(red[2], red[3]));
    float e[4], l = 0.f;
    #pragma unroll
    for (int i = 0; i < 4; ++i) { e[i] = expf(v[i] - m); l += e[i]; }
    #pragma unroll
    for (int off = 32; off > 0; off >>= 1) l += __shfl_xor(l, off);
    if ((t & 63) == 0) red[4 + (t >> 6)] = l;
    __syncthreads();
    l = red[4] + red[5] + red[6] + red[7];
    float inv = 1.f / l;
    #pragma unroll
    for (int i = 0; i < 4; ++i) attn[b * S + i * 256 + t] = e[i] * inv;
}

// ============ k_ctxp: partial context over s-chunks ============
__global__ void k_ctxp(const float* __restrict__ attn, const float* __restrict__ enc,
                       float* __restrict__ par) {
    int b = blockIdx.x >> 5, ch = blockIdx.x & 31;
    int t = threadIdx.x;
    float a0 = 0.f, a1 = 0.f;
    for (int si = 0; si < 32; ++si) {
        int s = ch * 32 + si;
        float a = attn[b * S + s];
        const float* eb = enc + ((long long)(s * 32 + b)) * H;
        a0 += a * eb[t];
        a1 += a * eb[256 + t];
    }
    float* p = par + (long long)(ch * 32 + b) * H;
    p[t] = a0;
    p[256 + t] = a1;
}

// ============ k_ctxr: reduce 32 chunks -> context ============
__global__ void k_ctxr(const float* __restrict__ par, float* __restrict__ ctxOut,
                       float* __restrict__ yT) {
    int idx = blockIdx.x * 256 + threadIdx.x;    // 0..16383
    int b = idx >> 9, h = idx & (H - 1);
    float s = 0.f;
    #pragma unroll 4
    for (int c = 0; c < 32; ++c) s += par[c * 16384 + b * H + h];
    ctxOut[b * H + h] = s;
    yT[(H + h) * 32 + b] = s;                    // y second half
}

// ============ k_gemm: logits[b][v] = y_b . Wout_v + bout_v ============
// 64 v-rows per block; 256 thr = 8 kg x 4 bg x 8 vg; thread tile 8v x 8b.
// Round 2 rewrite: all staging via global_load_lds (16B, direct HBM->LDS).
//   - removes the 12-float4 (48 VGPR) staging round trip that pushed live
//     regs past the 128 allocation -> scratch spills (358 MB WRITE_SIZE,
//     VALUBusy 8%, 1.6 TB/s).  Peak live now ~110 (acc 64 + ya/yb 32).
//   - W tile is linear [64][128] (global_load_lds needs contiguous dest);
//     bank conflicts handled by XOR swizzle on 16B slots: phys = log ^ (row&7),
//     applied to the *global source* address at stage time and to the
//     ds_read_b128 address at compute time (both-sides-or-neither).
//   - YS [128][32] stays linear (reads were conflict-free already).
#define RED_WRITE(reg) { float* rr = SM + (reg) * 2112;                       \
    _Pragma("unroll") for (int d = 0; d < 8; ++d) { int vl = vg + 8 * d;      \
    _Pragma("unroll") for (int e = 0; e < 8; ++e)                             \
        rr[vl * 33 + bg * 8 + e] = acc[d][e]; } }
#define RED_ADD(reg) { float* rr = SM + (reg) * 2112;                         \
    _Pragma("unroll") for (int d = 0; d < 8; ++d) { int vl = vg + 8 * d;      \
    _Pragma("unroll") for (int e = 0; e < 8; ++e)                             \
        acc[d][e] += rr[vl * 33 + bg * 8 + e]; } }

__global__ __launch_bounds__(256, 2)
void k_gemm(const float* __restrict__ Wout, const float* __restrict__ yTg,
            const float* __restrict__ bout, float* __restrict__ out) {
    __shared__ float SM[64 * 128 + 128 * 32];   // WT [64][128] swizzled + YS [128][32]
    float* WT = SM;
    float* YS = SM + 8192;
    int tid = threadIdx.x;
    int v0 = blockIdx.x * 64;
    int kg = tid >> 5;
    int bg = (tid >> 3) & 3;
    int vg = tid & 7;
    int lane = tid & 63;
    int wid = tid >> 6;
    float acc[8][8];
    #pragma unroll
    for (int d = 0; d < 8; ++d)
        #pragma unroll
        for (int e = 0; e < 8; ++e) acc[d][e] = 0.f;

    for (int kc = 0; kc < 1024; kc += 128) {
        // --- async stage W tile: wave wid covers rows [wid*16, wid*16+16) ---
        // one call = 1 KB = 2 rows of 512B; lane l -> row r0+(l>>5), phys slot l&31.
        // global src pre-swizzled: logical slot = (l&31) ^ (row&7).
        #pragma unroll
        for (int c = 0; c < 8; ++c) {
            int r0 = wid * 16 + c * 2;
            int row = r0 + (lane >> 5);
            int slog = (lane & 31) ^ (row & 7);
            int gv = v0 + row;
            if (gv >= V) gv = V - 1;      // clamp: garbage row, masked at store
            int ldsoff = __builtin_amdgcn_readfirstlane(r0 * 128);
            gld16(Wout + (long long)gv * 1024 + kc + slog * 4, WT + ldsoff);
        }
        // --- async stage Y tile: 16 KB linear, 4 calls of 1 KB per wave ---
        #pragma unroll
        for (int c = 0; c < 4; ++c) {
            int off = (wid * 4 + c) * 256;
            int ldsoff = __builtin_amdgcn_readfirstlane(off);
            gld16(yTg + kc * 32 + off + lane * 4, YS + ldsoff);
        }
        __syncthreads();   // drains vmcnt -> LDS tiles complete

        // --- compute: this thread's k range = [kg*16, kg*16+16), in 4-groups ---
        #pragma unroll
        for (int g = 0; g < 4; ++g) {
            int k0 = kg * 16 + g * 4;
            float4 ya[4], yb[4];
            #pragma unroll
            for (int kk = 0; kk < 4; ++kk) {
                ya[kk] = *(const float4*)(YS + (k0 + kk) * 32 + bg * 8);
                yb[kk] = *(const float4*)(YS + (k0 + kk) * 32 + bg * 8 + 4);
            }
            int sphys = ((kg << 2) + g) ^ vg;   // swizzled 16B slot for this thread
            #pragma unroll
            for (int d = 0; d < 8; ++d) {
                float4 w4 = *(const float4*)(WT + (vg + 8 * d) * 128 + (sphys << 2));
                acc[d][0] += w4.x * ya[0].x + w4.y * ya[1].x + w4.z * ya[2].x + w4.w * ya[3].x;
                acc[d][1] += w4.x * ya[0].y + w4.y * ya[1].y + w4.z * ya[2].y + w4.w * ya[3].y;
                acc[d][2] += w4.x * ya[0].z + w4.y * ya[1].z + w4.z * ya[2].z + w4.w * ya[3].z;
                acc[d][3] += w4.x * ya[0].w + w4.y * ya[1].w + w4.z * ya[2].w + w4.w * ya[3].w;
                acc[d][4] += w4.x * yb[0].x + w4.y * yb[1].x + w4.z * yb[2].x + w4.w * yb[3].x;
                acc[d][5] += w4.x * yb[0].y + w4.y * yb[1].y + w4.z * yb[2].y + w4.w * yb[3].y;
                acc[d][6] += w4.x * yb[0].z + w4.y * yb[1].z + w4.z * yb[2].z + w4.w * yb[3].z;
                acc[d][7] += w4.x * yb[0].w + w4.y * yb[1].w + w4.z * yb[2].w + w4.w * yb[3].w;
            }
        }
        __syncthreads();
    }

    // tree-reduce the 8 kg partials in LDS (SM reused; region stride 2112)
    if (kg >= 4) RED_WRITE(kg - 4);
    __syncthreads();
    if (kg < 4) RED_ADD(kg);
    __syncthreads();
    if (kg >= 2 && kg < 4) RED_WRITE(kg - 2);
    __syncthreads();
    if (kg < 2) RED_ADD(kg);
    __syncthreads();
    if (kg == 1) RED_WRITE(0);
    __syncthreads();
    if (kg == 0) {
        RED_ADD(0);
        #pragma unroll
        for (int d = 0; d < 8; ++d) {
            int gv = v0 + vg + 8 * d;
            if (gv < V) {
                float bo = bout[gv];
                #pragma unroll
                for (int e = 0; e < 8; ++e)
                    out[(long long)(bg * 8 + e) * V + gv] = acc[d][e] + bo;
            }
        }
    }
}

// ============ k_lsep: per (b, chunk) online max/sumexp over logits ============
__global__ void k_lsep(const float* __restrict__ out, float* __restrict__ lsep) {
    __shared__ float rm[4], rl[4];
    int b = blockIdx.x >> 4, ch = blockIdx.x & 15;
    int t = threadIdx.x;
    int start = ch * 3125, end = start + 3125;
    float m = -1e30f, l = 0.f;
    for (int v = start + t; v < end; v += 256) {
        float x = out[(long long)b * V + v];
        float nm = fmaxf(m, x);
        l = l * expf(m - nm) + expf(x - nm);
        m = nm;
    }
    #pragma unroll
    for (int off = 32; off > 0; off >>= 1) {
        float m2 = __shfl_xor(m, off);
        float l2 = __shfl_xor(l, off);
        float nm = fmaxf(m, m2);
        l = l * expf(m - nm) + l2 * expf(m2 - nm);
        m = nm;
    }
    if ((t & 63) == 0) { rm[t >> 6] = m; rl[t >> 6] = l; }
    __syncthreads();
    if (t == 0) {
        m = rm[0]; l = rl[0];
        for (int i = 1; i < 4; ++i) {
            float nm = fmaxf(m, rm[i]);
            l = l * expf(m - nm) + rl[i] * expf(rm[i] - nm);
            m = nm;
        }
        lsep[(b * 16 + ch) * 2] = m;
        lsep[(b * 16 + ch) * 2 + 1] = l;
    }
}

// ============ k_final: merge lse chunks, out = logits - lse[b] (in place) ====
__global__ void k_final(const float* __restrict__ lsep, float* __restrict__ out) {
    __shared__ float lse[32];
    int t = threadIdx.x;
    if (t < 32) {
        float m = lsep[t * 32], l = lsep[t * 32 + 1];
        for (int i = 1; i < 16; ++i) {
            float m2 = lsep[t * 32 + i * 2], l2 = lsep[t * 32 + i * 2 + 1];
            float nm = fmaxf(m, m2);
            l = l * expf(m - nm) + l2 * expf(m2 - nm);
            m = nm;
        }
        lse[t] = m + logf(l);
    }
    __syncthreads();
    int idx0 = blockIdx.x * 2048 + t;
    #pragma unroll
    for (int i = 0; i < 8; ++i) {
        int idx = idx0 + i * 256;
        if (idx < B * V) {
            int b = idx / V;
            out[idx] -= lse[b];
        }
    }
}

extern "C" void kernel_launch(void* const* d_in, const int* in_sizes, int n_in,
                              void* d_out, int out_size, void* d_ws, size_t ws_size,
                              hipStream_t stream) {
    const int*   wi   = (const int*)d_in[0];
    const float* lc   = (const float*)d_in[1];
    const float* h0   = (const float*)d_in[2];
    const float* c0   = (const float*)d_in[3];
    const float* enc  = (const float*)d_in[4];
    const float* emb  = (const float*)d_in[5];
    const float* Wih  = (const float*)d_in[6];
    const float* Whh  = (const float*)d_in[7];
    const float* bih  = (const float*)d_in[8];
    const float* bhh  = (const float*)d_in[9];
    const float* Wa   = (const float*)d_in[10];
    // d_in[11] = b_a: provably cancels in softmax -> unused
    const float* Wout = (const float*)d_in[12];
    const float* bout = (const float*)d_in[13];
    float* out = (float*)d_out;
    float* ws  = (float*)d_ws;

    float* zT   = ws + ZT_OFF;
    float* gT   = ws + GT_OFF;
    float* cT   = ws + CT_OFF;
    float* q    = ws + Q_OFF;
    float* yT   = ws + YT_OFF;
    float* sc   = ws + SC_OFF;
    float* par  = ws + PAR_OFF;
    float* lsep = ws + LSEP_OFF;

    k_prep<<<256, 256, 0, stream>>>(wi, lc, h0, emb, Wa, zT, q);
    k_gates<<<2048, 256, 0, stream>>>(zT, Wih, Whh, bih, bhh, gT);
    k_point<<<64, 256, 0, stream>>>(gT, c0, 0, zT, cT, yT, out + DO_H, out + DO_C);
    k_gates<<<2048, 256, 0, stream>>>(zT, Wih, Whh, bih, bhh, gT);
    k_point<<<64, 256, 0, stream>>>(gT, cT, 1, zT, cT, yT, out + DO_H, out + DO_C);
    k_scores<<<8192, 256, 0, stream>>>(q, enc, sc);
    k_softmax<<<32, 256, 0, stream>>>(sc, out + DO_ATTN);
    k_ctxp<<<1024, 256, 0, stream>>>(out + DO_ATTN, enc, par);
    k_ctxr<<<64, 256, 0, stream>>>(par, out + DO_CTX, yT);
    k_gemm<<<(V + 63) / 64, 256, 0, stream>>>(Wout, yT, bout, out + DO_OUT);
    k_lsep<<<512, 256, 0, stream>>>(out + DO_OUT, lsep);
    k_final<<<782, 256, 0, stream>>>(lsep, out + DO_OUT);
}

// Round 2
// 623.381 us; speedup vs baseline: 1.3700x; 1.3700x over previous
//
#include <hip/hip_runtime.h>
#include <math.h>

#define H 512
#define B 32
#define S 1024
#define V 50000

// ---- workspace layout (float offsets) ----
#define ZT_OFF   0         // zT [1536][32]
#define GT_OFF   49152     // gatesT [2048][32]
#define CT_OFF   114688    // cT [512][32]
#define Q_OFF    131072    // q [32][512]
#define YT_OFF   147456    // yT [1024][32]
#define SC_OFF   180224    // scores [32][1024]
#define PAR_OFF  212992    // partial ctx [32][32][512]
#define LSEP_OFF 737280    // lse partials [32][16][2]

// ---- d_out layout (float offsets) ----
#define DO_OUT   0         // [B][V] log-softmax
#define DO_CTX   1600000   // [B][H]
#define DO_H     1616384   // [B][H]
#define DO_C     1632768   // [B][H]
#define DO_ATTN  1649152   // [B][S]

// async 16B global->LDS (gfx950). LDS dest = base + lane*16 (linear, wave-level).
__device__ __forceinline__ void gld16(const float* g, float* l) {
    __builtin_amdgcn_global_load_lds(
        (const __attribute__((address_space(1))) void*)g,
        (__attribute__((address_space(3))) void*)l,
        16, 0, 0);
}

// ============ k_prep: zT fill + q = we @ W_a (4-way k-split) ============
// grid 256: b = blk>>3, hq = blk&7 (64 h per block); 256 thr = 4 kg x 64 hl
__global__ void k_prep(const int* __restrict__ wi, const float* __restrict__ lc,
                       const float* __restrict__ h0, const float* __restrict__ emb,
                       const float* __restrict__ Wa,
                       float* __restrict__ zT, float* __restrict__ q) {
    __shared__ float ech[512];
    __shared__ float red[4][64];
    int t = threadIdx.x;
    int b = blockIdx.x >> 3, hq = blockIdx.x & 7;
    int hl = t & 63, kg = t >> 6;
    int h = hq * 64 + hl;
    const float* er = emb + (long long)wi[b] * H;
    ech[t] = er[t];
    ech[256 + t] = er[256 + t];
    __syncthreads();
    if (kg == 0)      zT[h * 32 + b]           = ech[h];          // x part 1
    else if (kg == 1) zT[(H + h) * 32 + b]     = lc[b * H + h];   // x part 2
    else if (kg == 2) zT[(2 * H + h) * 32 + b] = h0[b * H + h];   // hidden
    float acc = 0.f;
    #pragma unroll 8
    for (int j = 0; j < 128; ++j) {
        int k = kg * 128 + j;
        acc += ech[k] * Wa[k * H + h];
    }
    red[kg][hl] = acc;
    __syncthreads();
    if (kg == 0) q[b * H + h] = red[0][hl] + red[1][hl] + red[2][hl] + red[3][hl];
}

// ============ k_gates: one block per gate row r; gatesT[r][b] ============
__global__ void k_gates(const float* __restrict__ zT, const float* __restrict__ Wih,
                        const float* __restrict__ Whh, const float* __restrict__ bih,
                        const float* __restrict__ bhh, float* __restrict__ gT) {
    __shared__ float red[8][32];
    int r = blockIdx.x;                 // 0..2047
    int t = threadIdx.x;
    int kg = t >> 5, b = t & 31;
    int k0 = kg * 192;
    const float* wih_r = Wih + (long long)r * 1024;
    const float* whh_r = Whh + (long long)r * 512;
    float acc = 0.f;
    int n_ih = (k0 < 1024) ? ((1024 - k0 < 192) ? (1024 - k0) : 192) : 0;
    #pragma unroll 4
    for (int j = 0; j < n_ih; ++j) {
        int k = k0 + j;
        acc += wih_r[k] * zT[k * 32 + b];
    }
    #pragma unroll 4
    for (int j = n_ih; j < 192; ++j) {
        int k = k0 + j;
        acc += whh_r[k - 1024] * zT[k * 32 + b];
    }
    red[kg][b] = acc;
    __syncthreads();
    if (t < 32) {
        float s = bih[r] + bhh[r];
        #pragma unroll
        for (int kk = 0; kk < 8; ++kk) s += red[kk][t];
        gT[r * 32 + t] = s;
    }
}

// ============ k_point: LSTM pointwise. layer 0 feeds zT, layer 1 finalizes ====
__global__ void k_point(const float* __restrict__ gT, const float* __restrict__ cprev,
                        int layer, float* __restrict__ zT, float* __restrict__ cT,
                        float* __restrict__ yT, float* __restrict__ hOut,
                        float* __restrict__ cOut) {
    int t = blockIdx.x * 256 + threadIdx.x;      // 0..16383
    int b = t & 31, hi = t >> 5;
    float gi = gT[hi * 32 + b];
    float gf = gT[(512 + hi) * 32 + b];
    float gg = gT[(1024 + hi) * 32 + b];
    float go = gT[(1536 + hi) * 32 + b];
    float si = 1.f / (1.f + expf(-gi));
    float sf = 1.f / (1.f + expf(-gf));
    float so = 1.f / (1.f + expf(-go));
    float c = (layer == 0) ? cprev[b * H + hi] : cprev[hi * 32 + b];
    float cn = sf * c + si * tanhf(gg);
    float hn = so * tanhf(cn);
    if (layer == 0) {
        zT[hi * 32 + b] = hn;                 // next x part 1
        zT[(2 * H + hi) * 32 + b] = hn;       // next hidden
        cT[hi * 32 + b] = cn;
    } else {
        yT[hi * 32 + b] = hn;                 // y = [h2, ctx], first half
        hOut[b * H + hi] = hn;
        cOut[b * H + hi] = cn;
    }
}

// ============ k_scores: one wave per (b,s) dot(q_b, enc_sb) ============
__global__ void k_scores(const float* __restrict__ q, const float* __restrict__ enc,
                         float* __restrict__ sc) {
    int w = (blockIdx.x * 256 + threadIdx.x) >> 6;   // 0..32767
    int lane = threadIdx.x & 63;
    int b = w >> 10, s = w & 1023;
    const float4* e4 = (const float4*)(enc + ((long long)(s * 32 + b)) * H);
    const float4* q4 = (const float4*)(q + b * H);
    float4 a0 = e4[lane * 2], a1 = e4[lane * 2 + 1];
    float4 b0 = q4[lane * 2], b1 = q4[lane * 2 + 1];
    float v = a0.x * b0.x + a0.y * b0.y + a0.z * b0.z + a0.w * b0.w
            + a1.x * b1.x + a1.y * b1.y + a1.z * b1.z + a1.w * b1.w;
    #pragma unroll
    for (int off = 32; off > 0; off >>= 1) v += __shfl_xor(v, off);
    if (lane == 0) sc[b * S + s] = v;
}

// ============ k_softmax: block per b over S=1024 ============
__global__ void k_softmax(const float* __restrict__ sc, float* __restrict__ attn) {
    __shared__ float red[8];
    int b = blockIdx.x, t = threadIdx.x;
    float v[4];
    float m = -1e30f;
    #pragma unroll
    for (int i = 0; i < 4; ++i) {
        v[i] = sc[b * S + i * 256 + t];
        m = fmaxf(m, v[i]);
    }
    #pragma unroll
    for (int off = 32; off > 0; off >>= 1) m = fmaxf(m, __shfl_xor(m, off));
    if ((t & 63) == 0) red[t >> 6] = m;
    __syncthreads();
    m = fmaxf(fmaxf(red[0], red[1]), fmaxf(red[2], red[3]));
    float e[4], l = 0.f;
    #pragma unroll
    for (int i = 0; i < 4; ++i) { e[i] = expf(v[i] - m); l += e[i]; }
    #pragma unroll
    for (int off = 32; off > 0; off >>= 1) l += __shfl_xor(l, off);
    if ((t & 63) == 0) red[4 + (t >> 6)] = l;
    __syncthreads();
    l = red[4] + red[5] + red[6] + red[7];
    float inv = 1.f / l;
    #pragma unroll
    for (int i = 0; i < 4; ++i) attn[b * S + i * 256 + t] = e[i] * inv;
}

// ============ k_ctxp: partial context over s-chunks ============
__global__ void k_ctxp(const float* __restrict__ attn, const float* __restrict__ enc,
                       float* __restrict__ par) {
    int b = blockIdx.x >> 5, ch = blockIdx.x & 31;
    int t = threadIdx.x;
    float a0 = 0.f, a1 = 0.f;
    for (int si = 0; si < 32; ++si) {
        int s = ch * 32 + si;
        float a = attn[b * S + s];
        const float* eb = enc + ((long long)(s * 32 + b)) * H;
        a0 += a * eb[t];
        a1 += a * eb[256 + t];
    }
    float* p = par + (long long)(ch * 32 + b) * H;
    p[t] = a0;
    p[256 + t] = a1;
}

// ============ k_ctxr: reduce 32 chunks -> context ============
__global__ void k_ctxr(const float* __restrict__ par, float* __restrict__ ctxOut,
                       float* __restrict__ yT) {
    int idx = blockIdx.x * 256 + threadIdx.x;    // 0..16383
    int b = idx >> 9, h = idx & (H - 1);
    float s = 0.f;
    #pragma unroll 4
    for (int c = 0; c < 32; ++c) s += par[c * 16384 + b * H + h];
    ctxOut[b * H + h] = s;
    yT[(H + h) * 32 + b] = s;                    // y second half
}

// ============ k_gemm: logits[b][v] = y_b . Wout_v + bout_v ============
// Round 2: double-buffered 2-phase pipeline (T3 minimum recipe), BK=64, 16 chunks.
//   - prev rounds were latency-serialized: single-buffer stage->barrier->compute
//     left waves idle >90% (426us vs ~60us phase-serial floor).
//   - W staged via gld16 (read-once data, zero staging regs); Y staged via
//     regs (hot 128KB -> L2 reuse; round-1 showed gld16 loses L2 for Y:
//     FETCH +123MB ~= Y traffic).  Issue-early/write-late (T14).
//   - W tile [64 rows][64 k] per buf, 16B-slot XOR swizzle phys = log ^ (row&15)
//     applied on global source at stage + on ds_read at compute (both-sides).
//   - LDS 48KB total -> 3 blocks/CU; one __syncthreads per chunk.
// thread map: kg=tid>>5 (8 k-slices of 8), bg=(tid>>3)&3 (8 b each), vg=tid&7.
#define RED_WRITE(reg) { float* rr = SM + (reg) * 2112;                       \
    _Pragma("unroll") for (int d = 0; d < 8; ++d) { int vl = vg + 8 * d;      \
    _Pragma("unroll") for (int e = 0; e < 8; ++e)                             \
        rr[vl * 33 + bg * 8 + e] = acc[d][e]; } }
#define RED_ADD(reg) { float* rr = SM + (reg) * 2112;                         \
    _Pragma("unroll") for (int d = 0; d < 8; ++d) { int vl = vg + 8 * d;      \
    _Pragma("unroll") for (int e = 0; e < 8; ++e)                             \
        acc[d][e] += rr[vl * 33 + bg * 8 + e]; } }

__global__ __launch_bounds__(256, 2)
void k_gemm(const float* __restrict__ Wout, const float* __restrict__ yTg,
            const float* __restrict__ bout, float* __restrict__ out) {
    __shared__ float SM[12288];            // WS: 2 x 4096 @ 0; YS: 2 x 2048 @ 8192
    int tid = threadIdx.x;
    int v0 = blockIdx.x * 64;
    int kg = tid >> 5;
    int bg = (tid >> 3) & 3;
    int vg = tid & 7;
    int lane = tid & 63;
    int wid = tid >> 6;
    float acc[8][8];
    #pragma unroll
    for (int d = 0; d < 8; ++d)
        #pragma unroll
        for (int e = 0; e < 8; ++e) acc[d][e] = 0.f;

    // W-stage lane geometry (constant across chunks)
    int srow[4], sslog[4], sdst[4];
    #pragma unroll
    for (int c = 0; c < 4; ++c) {
        int r0 = wid * 16 + c * 4;
        int row = r0 + (lane >> 4);
        srow[c] = row;
        sslog[c] = (lane & 15) ^ (row & 15);
        sdst[c] = __builtin_amdgcn_readfirstlane(r0 * 64);
    }

    // ---- prologue: stage chunk 0 into buf 0 ----
    {
        float4 ya = *(const float4*)(yTg + tid * 8);
        float4 yb = *(const float4*)(yTg + tid * 8 + 4);
        #pragma unroll
        for (int c = 0; c < 4; ++c) {
            int gv = v0 + srow[c];
            if (gv >= V) gv = V - 1;
            gld16(Wout + (long long)gv * 1024 + sslog[c] * 4, SM + sdst[c]);
        }
        *(float4*)(SM + 8192 + tid * 8) = ya;
        *(float4*)(SM + 8192 + tid * 8 + 4) = yb;
    }
    __syncthreads();

    int cur = 0;
    for (int t = 0; t < 16; ++t) {
        int nxt = cur ^ 1;
        float4 ya_n, yb_n;
        bool more = (t < 15);
        if (more) {
            int kc = (t + 1) * 64;
            // issue next Y loads (to regs) and next W gld16 before compute
            ya_n = *(const float4*)(yTg + kc * 32 + tid * 8);
            yb_n = *(const float4*)(yTg + kc * 32 + tid * 8 + 4);
            #pragma unroll
            for (int c = 0; c < 4; ++c) {
                int gv = v0 + srow[c];
                if (gv >= V) gv = V - 1;
                gld16(Wout + (long long)gv * 1024 + kc + sslog[c] * 4,
                      SM + nxt * 4096 + sdst[c]);
            }
        }
        // ---- compute chunk t from buf[cur] ----
        const float* WT = SM + cur * 4096;
        const float* YS = SM + 8192 + cur * 2048;
        #pragma unroll
        for (int g = 0; g < 2; ++g) {
            int k0 = kg * 8 + g * 4;
            float4 ya[4], yb[4];
            #pragma unroll
            for (int kk = 0; kk < 4; ++kk) {
                ya[kk] = *(const float4*)(YS + (k0 + kk) * 32 + bg * 8);
                yb[kk] = *(const float4*)(YS + (k0 + kk) * 32 + bg * 8 + 4);
            }
            #pragma unroll
            for (int d = 0; d < 8; ++d) {
                int r = vg + 8 * d;
                int phys = (kg * 2 + g) ^ (r & 15);
                float4 w4 = *(const float4*)(WT + r * 64 + phys * 4);
                acc[d][0] += w4.x * ya[0].x + w4.y * ya[1].x + w4.z * ya[2].x + w4.w * ya[3].x;
                acc[d][1] += w4.x * ya[0].y + w4.y * ya[1].y + w4.z * ya[2].y + w4.w * ya[3].y;
                acc[d][2] += w4.x * ya[0].z + w4.y * ya[1].z + w4.z * ya[2].z + w4.w * ya[3].z;
                acc[d][3] += w4.x * ya[0].w + w4.y * ya[1].w + w4.z * ya[2].w + w4.w * ya[3].w;
                acc[d][4] += w4.x * yb[0].x + w4.y * yb[1].x + w4.z * yb[2].x + w4.w * yb[3].x;
                acc[d][5] += w4.x * yb[0].y + w4.y * yb[1].y + w4.z * yb[2].y + w4.w * yb[3].y;
                acc[d][6] += w4.x * yb[0].z + w4.y * yb[1].z + w4.z * yb[2].z + w4.w * yb[3].z;
                acc[d][7] += w4.x * yb[0].w + w4.y * yb[1].w + w4.z * yb[2].w + w4.w * yb[3].w;
            }
        }
        if (more) {
            // write-late: deposit next Y chunk (waits only the 2 y-loads;
            // gld16s stay in flight until the barrier drain)
            *(float4*)(SM + 8192 + nxt * 2048 + tid * 8) = ya_n;
            *(float4*)(SM + 8192 + nxt * 2048 + tid * 8 + 4) = yb_n;
        }
        __syncthreads();     // drains vmcnt (W staged) + orders buffers
        cur = nxt;
    }

    // tree-reduce the 8 kg partials in LDS (SM reused; 4 regions x 2112 floats)
    if (kg >= 4) RED_WRITE(kg - 4);
    __syncthreads();
    if (kg < 4) RED_ADD(kg);
    __syncthreads();
    if (kg >= 2 && kg < 4) RED_WRITE(kg - 2);
    __syncthreads();
    if (kg < 2) RED_ADD(kg);
    __syncthreads();
    if (kg == 1) RED_WRITE(0);
    __syncthreads();
    if (kg == 0) {
        RED_ADD(0);
        #pragma unroll
        for (int d = 0; d < 8; ++d) {
            int gv = v0 + vg + 8 * d;
            if (gv < V) {
                float bo = bout[gv];
                #pragma unroll
                for (int e = 0; e < 8; ++e)
                    out[(long long)(bg * 8 + e) * V + gv] = acc[d][e] + bo;
            }
        }
    }
}

// ============ k_lsep: per (b, chunk) online max/sumexp over logits ============
__global__ void k_lsep(const float* __restrict__ out, float* __restrict__ lsep) {
    __shared__ float rm[4], rl[4];
    int b = blockIdx.x >> 4, ch = blockIdx.x & 15;
    int t = threadIdx.x;
    int start = ch * 3125, end = start + 3125;
    float m = -1e30f, l = 0.f;
    for (int v = start + t; v < end; v += 256) {
        float x = out[(long long)b * V + v];
        float nm = fmaxf(m, x);
        l = l * expf(m - nm) + expf(x - nm);
        m = nm;
    }
    #pragma unroll
    for (int off = 32; off > 0; off >>= 1) {
        float m2 = __shfl_xor(m, off);
        float l2 = __shfl_xor(l, off);
        float nm = fmaxf(m, m2);
        l = l * expf(m - nm) + l2 * expf(m2 - nm);
        m = nm;
    }
    if ((t & 63) == 0) { rm[t >> 6] = m; rl[t >> 6] = l; }
    __syncthreads();
    if (t == 0) {
        m = rm[0]; l = rl[0];
        for (int i = 1; i < 4; ++i) {
            float nm = fmaxf(m, rm[i]);
            l = l * expf(m - nm) + rl[i] * expf(rm[i] - nm);
            m = nm;
        }
        lsep[(b * 16 + ch) * 2] = m;
        lsep[(b * 16 + ch) * 2 + 1] = l;
    }
}

// ============ k_final: merge lse chunks, out = logits - lse[b] (in place) ====
__global__ void k_final(const float* __restrict__ lsep, float* __restrict__ out) {
    __shared__ float lse[32];
    int t = threadIdx.x;
    if (t < 32) {
        float m = lsep[t * 32], l = lsep[t * 32 + 1];
        for (int i = 1; i < 16; ++i) {
            float m2 = lsep[t * 32 + i * 2], l2 = lsep[t * 32 + i * 2 + 1];
            float nm = fmaxf(m, m2);
            l = l * expf(m - nm) + l2 * expf(m2 - nm);
            m = nm;
        }
        lse[t] = m + logf(l);
    }
    __syncthreads();
    int idx0 = blockIdx.x * 2048 + t;
    #pragma unroll
    for (int i = 0; i < 8; ++i) {
        int idx = idx0 + i * 256;
        if (idx < B * V) {
            int b = idx / V;
            out[idx] -= lse[b];
        }
    }
}

extern "C" void kernel_launch(void* const* d_in, const int* in_sizes, int n_in,
                              void* d_out, int out_size, void* d_ws, size_t ws_size,
                              hipStream_t stream) {
    const int*   wi   = (const int*)d_in[0];
    const float* lc   = (const float*)d_in[1];
    const float* h0   = (const float*)d_in[2];
    const float* c0   = (const float*)d_in[3];
    const float* enc  = (const float*)d_in[4];
    const float* emb  = (const float*)d_in[5];
    const float* Wih  = (const float*)d_in[6];
    const float* Whh  = (const float*)d_in[7];
    const float* bih  = (const float*)d_in[8];
    const float* bhh  = (const float*)d_in[9];
    const float* Wa   = (const float*)d_in[10];
    // d_in[11] = b_a: provably cancels in softmax -> unused
    const float* Wout = (const float*)d_in[12];
    const float* bout = (const float*)d_in[13];
    float* out = (float*)d_out;
    float* ws  = (float*)d_ws;

    float* zT   = ws + ZT_OFF;
    float* gT   = ws + GT_OFF;
    float* cT   = ws + CT_OFF;
    float* q    = ws + Q_OFF;
    float* yT   = ws + YT_OFF;
    float* sc   = ws + SC_OFF;
    float* par  = ws + PAR_OFF;
    float* lsep = ws + LSEP_OFF;

    k_prep<<<256, 256, 0, stream>>>(wi, lc, h0, emb, Wa, zT, q);
    k_gates<<<2048, 256, 0, stream>>>(zT, Wih, Whh, bih, bhh, gT);
    k_point<<<64, 256, 0, stream>>>(gT, c0, 0, zT, cT, yT, out + DO_H, out + DO_C);
    k_gates<<<2048, 256, 0, stream>>>(zT, Wih, Whh, bih, bhh, gT);
    k_point<<<64, 256, 0, stream>>>(gT, cT, 1, zT, cT, yT, out + DO_H, out + DO_C);
    k_scores<<<8192, 256, 0, stream>>>(q, enc, sc);
    k_softmax<<<32, 256, 0, stream>>>(sc, out + DO_ATTN);
    k_ctxp<<<1024, 256, 0, stream>>>(out + DO_ATTN, enc, par);
    k_ctxr<<<64, 256, 0, stream>>>(par, out + DO_CTX, yT);
    k_gemm<<<(V + 63) / 64, 256, 0, stream>>>(Wout, yT, bout, out + DO_OUT);
    k_lsep<<<512, 256, 0, stream>>>(out + DO_OUT, lsep);
    k_final<<<782, 256, 0, stream>>>(lsep, out + DO_OUT);
}

// Round 4
// 589.392 us; speedup vs baseline: 1.4491x; 1.0577x over previous
//
#include <hip/hip_runtime.h>
#include <math.h>

#define H 512
#define B 32
#define S 1024
#define V 50000

// ---- workspace layout (float offsets) ----
#define ZT_OFF   0         // zT [1536][32]
#define GT_OFF   49152     // gatesT [2048][32]
#define CT_OFF   114688    // cT [512][32]
#define Q_OFF    131072    // q [32][512]
#define YT_OFF   147456    // yT [1024][32]
#define SC_OFF   180224    // scores [32][1024]
#define PAR_OFF  212992    // partial ctx [32][32][512]
#define LSEP_OFF 737280    // lse partials [32][16][2]

// ---- d_out layout (float offsets) ----
#define DO_OUT   0         // [B][V] log-softmax
#define DO_CTX   1600000   // [B][H]
#define DO_H     1616384   // [B][H]
#define DO_C     1632768   // [B][H]
#define DO_ATTN  1649152   // [B][S]

// async 16B global->LDS (gfx950). LDS dest = base + lane*16 (linear, wave-level).
__device__ __forceinline__ void gld16(const float* g, float* l) {
    __builtin_amdgcn_global_load_lds(
        (const __attribute__((address_space(1))) void*)g,
        (__attribute__((address_space(3))) void*)l,
        16, 0, 0);
}

// ============ k_prep: zT fill + q = we @ W_a (4-way k-split) ============
// grid 256: b = blk>>3, hq = blk&7 (64 h per block); 256 thr = 4 kg x 64 hl
__global__ void k_prep(const int* __restrict__ wi, const float* __restrict__ lc,
                       const float* __restrict__ h0, const float* __restrict__ emb,
                       const float* __restrict__ Wa,
                       float* __restrict__ zT, float* __restrict__ q) {
    __shared__ float ech[512];
    __shared__ float red[4][64];
    int t = threadIdx.x;
    int b = blockIdx.x >> 3, hq = blockIdx.x & 7;
    int hl = t & 63, kg = t >> 6;
    int h = hq * 64 + hl;
    const float* er = emb + (long long)wi[b] * H;
    ech[t] = er[t];
    ech[256 + t] = er[256 + t];
    __syncthreads();
    if (kg == 0)      zT[h * 32 + b]           = ech[h];          // x part 1
    else if (kg == 1) zT[(H + h) * 32 + b]     = lc[b * H + h];   // x part 2
    else if (kg == 2) zT[(2 * H + h) * 32 + b] = h0[b * H + h];   // hidden
    float acc = 0.f;
    #pragma unroll 8
    for (int j = 0; j < 128; ++j) {
        int k = kg * 128 + j;
        acc += ech[k] * Wa[k * H + h];
    }
    red[kg][hl] = acc;
    __syncthreads();
    if (kg == 0) q[b * H + h] = red[0][hl] + red[1][hl] + red[2][hl] + red[3][hl];
}

// ============ k_gates: one block per gate row r; gatesT[r][b] ============
__global__ void k_gates(const float* __restrict__ zT, const float* __restrict__ Wih,
                        const float* __restrict__ Whh, const float* __restrict__ bih,
                        const float* __restrict__ bhh, float* __restrict__ gT) {
    __shared__ float red[8][32];
    int r = blockIdx.x;                 // 0..2047
    int t = threadIdx.x;
    int kg = t >> 5, b = t & 31;
    int k0 = kg * 192;
    const float* wih_r = Wih + (long long)r * 1024;
    const float* whh_r = Whh + (long long)r * 512;
    float acc = 0.f;
    int n_ih = (k0 < 1024) ? ((1024 - k0 < 192) ? (1024 - k0) : 192) : 0;
    #pragma unroll 4
    for (int j = 0; j < n_ih; ++j) {
        int k = k0 + j;
        acc += wih_r[k] * zT[k * 32 + b];
    }
    #pragma unroll 4
    for (int j = n_ih; j < 192; ++j) {
        int k = k0 + j;
        acc += whh_r[k - 1024] * zT[k * 32 + b];
    }
    red[kg][b] = acc;
    __syncthreads();
    if (t < 32) {
        float s = bih[r] + bhh[r];
        #pragma unroll
        for (int kk = 0; kk < 8; ++kk) s += red[kk][t];
        gT[r * 32 + t] = s;
    }
}

// ============ k_point: LSTM pointwise. layer 0 feeds zT, layer 1 finalizes ====
__global__ void k_point(const float* __restrict__ gT, const float* __restrict__ cprev,
                        int layer, float* __restrict__ zT, float* __restrict__ cT,
                        float* __restrict__ yT, float* __restrict__ hOut,
                        float* __restrict__ cOut) {
    int t = blockIdx.x * 256 + threadIdx.x;      // 0..16383
    int b = t & 31, hi = t >> 5;
    float gi = gT[hi * 32 + b];
    float gf = gT[(512 + hi) * 32 + b];
    float gg = gT[(1024 + hi) * 32 + b];
    float go = gT[(1536 + hi) * 32 + b];
    float si = 1.f / (1.f + expf(-gi));
    float sf = 1.f / (1.f + expf(-gf));
    float so = 1.f / (1.f + expf(-go));
    float c = (layer == 0) ? cprev[b * H + hi] : cprev[hi * 32 + b];
    float cn = sf * c + si * tanhf(gg);
    float hn = so * tanhf(cn);
    if (layer == 0) {
        zT[hi * 32 + b] = hn;                 // next x part 1
        zT[(2 * H + hi) * 32 + b] = hn;       // next hidden
        cT[hi * 32 + b] = cn;
    } else {
        yT[hi * 32 + b] = hn;                 // y = [h2, ctx], first half
        hOut[b * H + hi] = hn;
        cOut[b * H + hi] = cn;
    }
}

// ============ k_scores: one wave per (b,s) dot(q_b, enc_sb) ============
__global__ void k_scores(const float* __restrict__ q, const float* __restrict__ enc,
                         float* __restrict__ sc) {
    int w = (blockIdx.x * 256 + threadIdx.x) >> 6;   // 0..32767
    int lane = threadIdx.x & 63;
    int b = w >> 10, s = w & 1023;
    const float4* e4 = (const float4*)(enc + ((long long)(s * 32 + b)) * H);
    const float4* q4 = (const float4*)(q + b * H);
    float4 a0 = e4[lane * 2], a1 = e4[lane * 2 + 1];
    float4 b0 = q4[lane * 2], b1 = q4[lane * 2 + 1];
    float v = a0.x * b0.x + a0.y * b0.y + a0.z * b0.z + a0.w * b0.w
            + a1.x * b1.x + a1.y * b1.y + a1.z * b1.z + a1.w * b1.w;
    #pragma unroll
    for (int off = 32; off > 0; off >>= 1) v += __shfl_xor(v, off);
    if (lane == 0) sc[b * S + s] = v;
}

// ============ k_softmax: block per b over S=1024 ============
__global__ void k_softmax(const float* __restrict__ sc, float* __restrict__ attn) {
    __shared__ float red[8];
    int b = blockIdx.x, t = threadIdx.x;
    float v[4];
    float m = -1e30f;
    #pragma unroll
    for (int i = 0; i < 4; ++i) {
        v[i] = sc[b * S + i * 256 + t];
        m = fmaxf(m, v[i]);
    }
    #pragma unroll
    for (int off = 32; off > 0; off >>= 1) m = fmaxf(m, __shfl_xor(m, off));
    if ((t & 63) == 0) red[t >> 6] = m;
    __syncthreads();
    m = fmaxf(fmaxf(red[0], red[1]), fmaxf(red[2], red[3]));
    float e[4], l = 0.f;
    #pragma unroll
    for (int i = 0; i < 4; ++i) { e[i] = expf(v[i] - m); l += e[i]; }
    #pragma unroll
    for (int off = 32; off > 0; off >>= 1) l += __shfl_xor(l, off);
    if ((t & 63) == 0) red[4 + (t >> 6)] = l;
    __syncthreads();
    l = red[4] + red[5] + red[6] + red[7];
    float inv = 1.f / l;
    #pragma unroll
    for (int i = 0; i < 4; ++i) attn[b * S + i * 256 + t] = e[i] * inv;
}

// ============ k_ctxp: partial context over s-chunks ============
__global__ void k_ctxp(const float* __restrict__ attn, const float* __restrict__ enc,
                       float* __restrict__ par) {
    int b = blockIdx.x >> 5, ch = blockIdx.x & 31;
    int t = threadIdx.x;
    float a0 = 0.f, a1 = 0.f;
    for (int si = 0; si < 32; ++si) {
        int s = ch * 32 + si;
        float a = attn[b * S + s];
        const float* eb = enc + ((long long)(s * 32 + b)) * H;
        a0 += a * eb[t];
        a1 += a * eb[256 + t];
    }
    float* p = par + (long long)(ch * 32 + b) * H;
    p[t] = a0;
    p[256 + t] = a1;
}

// ============ k_ctxr: reduce 32 chunks -> context ============
__global__ void k_ctxr(const float* __restrict__ par, float* __restrict__ ctxOut,
                       float* __restrict__ yT) {
    int idx = blockIdx.x * 256 + threadIdx.x;    // 0..16383
    int b = idx >> 9, h = idx & (H - 1);
    float s = 0.f;
    #pragma unroll 4
    for (int c = 0; c < 32; ++c) s += par[c * 16384 + b * H + h];
    ctxOut[b * H + h] = s;
    yT[(H + h) * 32 + b] = s;                    // y second half
}

// ============ k_gemm: logits[b][v] = y_b . Wout_v + bout_v ============
// Round 4 = round 3 resubmit (infra flake), hardened asm.
// Counted-vmcnt pipeline (T4).  Round-2 post-mortem: __syncthreads' vmcnt(0)
// drain serialized every chunk (29K cy/chunk vs 3K compute) -> 1 TB/s.
//   - BK=32, 32 chunks, 3 W bufs (depth-2 prefetch).  Per iter:
//     compute c(t) -> issue W(t+2) gld16 -> {s_waitcnt vmcnt(2); s_barrier}
//     in ONE asm block (W(t+1) lands, W(t+2) STAYS IN FLIGHT across the
//     barrier) -> sched_barrier(0) (rule #18: pin reordering).
//     WAR on buf[(t+2)%3]: closed by iter t-1's barrier (issue after compute).
//   - Y read directly from global (yT = 128KB, L2-hot; 8x amplification is
//     ~819MB L2 traffic, fine).  No Y LDS, no ds_write, no 2nd barrier.
//   - W swizzle: phys 16B slot = kg ^ vg (8 slots/row): conflict-free reads
//     (8 slots x 4 words = 32 banks; 4-lane same-address broadcast free).
//     Applied on pre-swizzled GLOBAL source at stage + on ds_read (rule 21).
//   - LDS 33KB (8448 floats: 3x2048 W bufs; reduce scratch 4x2112) -> 4 blk/CU.
// thread map: kg=tid>>5 (8 k-slices of 4), bg=(tid>>3)&3 (8 b each), vg=tid&7.
#define RED_WRITE(reg) { float* rr = SM + (reg) * 2112;                       \
    _Pragma("unroll") for (int d = 0; d < 8; ++d) { int vl = vg + 8 * d;      \
    _Pragma("unroll") for (int e = 0; e < 8; ++e)                             \
        rr[vl * 33 + bg * 8 + e] = acc[d][e]; } }
#define RED_ADD(reg) { float* rr = SM + (reg) * 2112;                         \
    _Pragma("unroll") for (int d = 0; d < 8; ++d) { int vl = vg + 8 * d;      \
    _Pragma("unroll") for (int e = 0; e < 8; ++e)                             \
        acc[d][e] += rr[vl * 33 + bg * 8 + e]; } }

__global__ __launch_bounds__(256, 2)
void k_gemm(const float* __restrict__ Wout, const float* __restrict__ yTg,
            const float* __restrict__ bout, float* __restrict__ out) {
    __shared__ float SM[8448];             // W bufs 3 x 2048 @ 0; reduce 4 x 2112
    int tid = threadIdx.x;
    int v0 = blockIdx.x * 64;
    int kg = tid >> 5;
    int bg = (tid >> 3) & 3;
    int vg = tid & 7;
    int lane = tid & 63;
    int wid = tid >> 6;
    float acc[8][8];
    #pragma unroll
    for (int d = 0; d < 8; ++d)
        #pragma unroll
        for (int e = 0; e < 8; ++e) acc[d][e] = 0.f;

    // W-stage lane geometry: wave wid stages rows [wid*16, wid*16+16).
    // gld16 #c: 8 rows of 128B; lane l -> row r0+(l>>3), phys slot l&7,
    // carries logical slot (l&7)^(row&7)  (pre-swizzled global source).
    long long gsrc[2]; int sdst[2];
    #pragma unroll
    for (int c = 0; c < 2; ++c) {
        int r0 = wid * 16 + c * 8;
        int row = r0 + (lane >> 3);
        int slog = (lane & 7) ^ (row & 7);
        int gv = v0 + row;
        if (gv >= V) gv = V - 1;           // clamp: garbage row, masked at store
        gsrc[c] = (long long)gv * 1024 + slog * 4;
        sdst[c] = __builtin_amdgcn_readfirstlane(r0 * 32);
    }

    // ---- prologue: stage chunks 0 and 1 ----
    #pragma unroll
    for (int c = 0; c < 2; ++c) gld16(Wout + gsrc[c], SM + sdst[c]);            // chunk 0 -> buf0
    #pragma unroll
    for (int c = 0; c < 2; ++c) gld16(Wout + gsrc[c] + 32, SM + 2048 + sdst[c]); // chunk 1 -> buf1
    asm volatile("s_waitcnt vmcnt(2)\n\ts_barrier" ::: "memory"); // c0 landed; c1 in flight
    __builtin_amdgcn_sched_barrier(0);

    int bcur = 0, bpre = 2;
    for (int t = 0; t < 32; ++t) {
        const float* WT = SM + bcur * 2048;
        // ---- compute chunk t: k = t*32 + kg*4 + kk ----
        const float* yp = yTg + (t * 32 + (kg << 2)) * 32 + bg * 8;
        float4 ya0 = *(const float4*)(yp);
        float4 yb0 = *(const float4*)(yp + 4);
        float4 ya1 = *(const float4*)(yp + 32);
        float4 yb1 = *(const float4*)(yp + 36);
        float4 ya2 = *(const float4*)(yp + 64);
        float4 yb2 = *(const float4*)(yp + 68);
        float4 ya3 = *(const float4*)(yp + 96);
        float4 yb3 = *(const float4*)(yp + 100);
        const float* wbase = WT + vg * 32 + ((kg ^ vg) << 2);
        #pragma unroll
        for (int d = 0; d < 8; ++d) {
            float4 w4 = *(const float4*)(wbase + d * 256);
            acc[d][0] += w4.x * ya0.x + w4.y * ya1.x + w4.z * ya2.x + w4.w * ya3.x;
            acc[d][1] += w4.x * ya0.y + w4.y * ya1.y + w4.z * ya2.y + w4.w * ya3.y;
            acc[d][2] += w4.x * ya0.z + w4.y * ya1.z + w4.z * ya2.z + w4.w * ya3.z;
            acc[d][3] += w4.x * ya0.w + w4.y * ya1.w + w4.z * ya2.w + w4.w * ya3.w;
            acc[d][4] += w4.x * yb0.x + w4.y * yb1.x + w4.z * yb2.x + w4.w * yb3.x;
            acc[d][5] += w4.x * yb0.y + w4.y * yb1.y + w4.z * yb2.y + w4.w * yb3.y;
            acc[d][6] += w4.x * yb0.z + w4.y * yb1.z + w4.z * yb2.z + w4.w * yb3.z;
            acc[d][7] += w4.x * yb0.w + w4.y * yb1.w + w4.z * yb2.w + w4.w * yb3.w;
        }
        // ---- prefetch chunk t+2 (clamped dummy at tail; never touches the
        //      live bufs: at t=30/31 targets bufs 2/0 while c(31) reads buf 1)
        int tn = t + 2; if (tn > 31) tn = 31;
        float* dst = SM + bpre * 2048;
        #pragma unroll
        for (int c = 0; c < 2; ++c) gld16(Wout + gsrc[c] + tn * 32, dst + sdst[c]);
        // counted wait: W(t+1) guaranteed landed, W(t+2) stays outstanding
        asm volatile("s_waitcnt vmcnt(2)\n\ts_barrier" ::: "memory");
        __builtin_amdgcn_sched_barrier(0);
        bcur = (bcur == 2) ? 0 : bcur + 1;
        bpre = (bpre == 2) ? 0 : bpre + 1;
    }
    // drain the tail dummies before reusing LDS as reduce scratch
    asm volatile("s_waitcnt vmcnt(0)\n\ts_barrier" ::: "memory");
    __builtin_amdgcn_sched_barrier(0);

    // tree-reduce the 8 kg partials in LDS (SM reused; 4 regions x 2112 floats)
    if (kg >= 4) RED_WRITE(kg - 4);
    __syncthreads();
    if (kg < 4) RED_ADD(kg);
    __syncthreads();
    if (kg >= 2 && kg < 4) RED_WRITE(kg - 2);
    __syncthreads();
    if (kg < 2) RED_ADD(kg);
    __syncthreads();
    if (kg == 1) RED_WRITE(0);
    __syncthreads();
    if (kg == 0) {
        RED_ADD(0);
        #pragma unroll
        for (int d = 0; d < 8; ++d) {
            int gv = v0 + vg + 8 * d;
            if (gv < V) {
                float bo = bout[gv];
                #pragma unroll
                for (int e = 0; e < 8; ++e)
                    out[(long long)(bg * 8 + e) * V + gv] = acc[d][e] + bo;
            }
        }
    }
}

// ============ k_lsep: per (b, chunk) online max/sumexp over logits ============
__global__ void k_lsep(const float* __restrict__ out, float* __restrict__ lsep) {
    __shared__ float rm[4], rl[4];
    int b = blockIdx.x >> 4, ch = blockIdx.x & 15;
    int t = threadIdx.x;
    int start = ch * 3125, end = start + 3125;
    float m = -1e30f, l = 0.f;
    for (int v = start + t; v < end; v += 256) {
        float x = out[(long long)b * V + v];
        float nm = fmaxf(m, x);
        l = l * expf(m - nm) + expf(x - nm);
        m = nm;
    }
    #pragma unroll
    for (int off = 32; off > 0; off >>= 1) {
        float m2 = __shfl_xor(m, off);
        float l2 = __shfl_xor(l, off);
        float nm = fmaxf(m, m2);
        l = l * expf(m - nm) + l2 * expf(m2 - nm);
        m = nm;
    }
    if ((t & 63) == 0) { rm[t >> 6] = m; rl[t >> 6] = l; }
    __syncthreads();
    if (t == 0) {
        m = rm[0]; l = rl[0];
        for (int i = 1; i < 4; ++i) {
            float nm = fmaxf(m, rm[i]);
            l = l * expf(m - nm) + rl[i] * expf(rm[i] - nm);
            m = nm;
        }
        lsep[(b * 16 + ch) * 2] = m;
        lsep[(b * 16 + ch) * 2 + 1] = l;
    }
}

// ============ k_final: merge lse chunks, out = logits - lse[b] (in place) ====
__global__ void k_final(const float* __restrict__ lsep, float* __restrict__ out) {
    __shared__ float lse[32];
    int t = threadIdx.x;
    if (t < 32) {
        float m = lsep[t * 32], l = lsep[t * 32 + 1];
        for (int i = 1; i < 16; ++i) {
            float m2 = lsep[t * 32 + i * 2], l2 = lsep[t * 32 + i * 2 + 1];
            float nm = fmaxf(m, m2);
            l = l * expf(m - nm) + l2 * expf(m2 - nm);
            m = nm;
        }
        lse[t] = m + logf(l);
    }
    __syncthreads();
    int idx0 = blockIdx.x * 2048 + t;
    #pragma unroll
    for (int i = 0; i < 8; ++i) {
        int idx = idx0 + i * 256;
        if (idx < B * V) {
            int b = idx / V;
            out[idx] -= lse[b];
        }
    }
}

extern "C" void kernel_launch(void* const* d_in, const int* in_sizes, int n_in,
                              void* d_out, int out_size, void* d_ws, size_t ws_size,
                              hipStream_t stream) {
    const int*   wi   = (const int*)d_in[0];
    const float* lc   = (const float*)d_in[1];
    const float* h0   = (const float*)d_in[2];
    const float* c0   = (const float*)d_in[3];
    const float* enc  = (const float*)d_in[4];
    const float* emb  = (const float*)d_in[5];
    const float* Wih  = (const float*)d_in[6];
    const float* Whh  = (const float*)d_in[7];
    const float* bih  = (const float*)d_in[8];
    const float* bhh  = (const float*)d_in[9];
    const float* Wa   = (const float*)d_in[10];
    // d_in[11] = b_a: provably cancels in softmax -> unused
    const float* Wout = (const float*)d_in[12];
    const float* bout = (const float*)d_in[13];
    float* out = (float*)d_out;
    float* ws  = (float*)d_ws;

    float* zT   = ws + ZT_OFF;
    float* gT   = ws + GT_OFF;
    float* cT   = ws + CT_OFF;
    float* q    = ws + Q_OFF;
    float* yT   = ws + YT_OFF;
    float* sc   = ws + SC_OFF;
    float* par  = ws + PAR_OFF;
    float* lsep = ws + LSEP_OFF;

    k_prep<<<256, 256, 0, stream>>>(wi, lc, h0, emb, Wa, zT, q);
    k_gates<<<2048, 256, 0, stream>>>(zT, Wih, Whh, bih, bhh, gT);
    k_point<<<64, 256, 0, stream>>>(gT, c0, 0, zT, cT, yT, out + DO_H, out + DO_C);
    k_gates<<<2048, 256, 0, stream>>>(zT, Wih, Whh, bih, bhh, gT);
    k_point<<<64, 256, 0, stream>>>(gT, cT, 1, zT, cT, yT, out + DO_H, out + DO_C);
    k_scores<<<8192, 256, 0, stream>>>(q, enc, sc);
    k_softmax<<<32, 256, 0, stream>>>(sc, out + DO_ATTN);
    k_ctxp<<<1024, 256, 0, stream>>>(out + DO_ATTN, enc, par);
    k_ctxr<<<64, 256, 0, stream>>>(par, out + DO_CTX, yT);
    k_gemm<<<(V + 63) / 64, 256, 0, stream>>>(Wout, yT, bout, out + DO_OUT);
    k_lsep<<<512, 256, 0, stream>>>(out + DO_OUT, lsep);
    k_final<<<782, 256, 0, stream>>>(lsep, out + DO_OUT);
}